// Round 8
// baseline (501.327 us; speedup 1.0000x reference)
//
#include <hip/hip_runtime.h>
#include <hip/hip_bf16.h>

#define NN 50000
#define EE 800000
#define DH 128
#define RDIM 32
#define RR 16
#define HRD 160
#define HSW 384            // HS row (ushort): [128 h | 128 S/agg | 128 RMacc]
#define SCAN_B ((NN + 255) / 256)

typedef __attribute__((ext_vector_type(8))) short bf16x8;
typedef __attribute__((ext_vector_type(4))) float f32x4;

__device__ __forceinline__ ushort f2b(float v) {      // f32 -> bf16 RNE
    uint u = __float_as_uint(v);
    return (ushort)((u + 0x7fffu + ((u >> 16) & 1u)) >> 16);
}
__device__ __forceinline__ float b2f(ushort b) { return __uint_as_float(((uint)b) << 16); }

// ---------------- CSR build ----------------
__global__ __launch_bounds__(256) void k_count(const int* __restrict__ dst,
                                               int* deg, int* ord) {
    int e = blockIdx.x * 256 + threadIdx.x;
    if (e < EE) ord[e] = atomicAdd(&deg[dst[e]], 1);
}

__global__ __launch_bounds__(256) void k_scan_part(const int* __restrict__ deg,
                                                   int* rp, int* bsum) {
    __shared__ int s[256];
    int tid = threadIdx.x;
    int i = blockIdx.x * 256 + tid;
    int v = (i < NN) ? deg[i] : 0;
    s[tid] = v;
    __syncthreads();
    for (int off = 1; off < 256; off <<= 1) {
        int t = (tid >= off) ? s[tid - off] : 0;
        __syncthreads();
        s[tid] += t;
        __syncthreads();
    }
    if (i < NN) rp[i] = s[tid] - v;
    if (tid == 255) bsum[blockIdx.x] = s[255];
}

__global__ __launch_bounds__(256) void k_scan_bsum(const int* __restrict__ bsum, int* boff) {
    __shared__ int s[256];
    int tid = threadIdx.x;
    int v = (tid < SCAN_B) ? bsum[tid] : 0;
    s[tid] = v;
    __syncthreads();
    for (int off = 1; off < 256; off <<= 1) {
        int t = (tid >= off) ? s[tid - off] : 0;
        __syncthreads();
        s[tid] += t;
        __syncthreads();
    }
    boff[tid] = s[tid] - v;
}

__global__ __launch_bounds__(256) void k_scan_add(const int* __restrict__ boff, int* rp) {
    int i = blockIdx.x * 256 + threadIdx.x;
    if (i < NN) rp[i] += boff[blockIdx.x];
    if (i == 0) rp[NN] = EE;
}

// col[p] = src | rel<<16  (src < 65536, rel < 16)
__global__ __launch_bounds__(256) void k_fill(const int* __restrict__ src,
                                              const int* __restrict__ dst,
                                              const int* __restrict__ rel,
                                              const int* __restrict__ ord,
                                              const int* __restrict__ rp,
                                              int* __restrict__ col) {
    int e = blockIdx.x * 256 + threadIdx.x;
    if (e < EE) {
        int p = rp[dst[e]] + ord[e];
        col[p] = src[e] | (rel[e] << 16);
    }
}

// ---------------- weight prep ----------------
__global__ __launch_bounds__(256) void k_prep_inWb(const float* __restrict__ w,
                                                   ushort* __restrict__ o) {
    int i = blockIdx.x * 256 + threadIdx.x;          // 16384
    o[i] = f2b(w[i]);
}

// B1[l][f][0..127] = msg_Wh[l][f][:] bf16
// RMt[l][c][r] = (rel_emb[l] @ msg_Wr[l].T)[r][c]   (TRANSPOSED: col-major over rel)
__global__ __launch_bounds__(256) void k_prep_msgWb(const float* __restrict__ msgW,
                                                    const float* __restrict__ relE,
                                                    ushort* __restrict__ B1,
                                                    float* __restrict__ RMt) {
    int t = threadIdx.x;                              // 1 block x 256
    int l = t >> 7, f = t & 127;
    const float* mw = msgW + (size_t)l * DH * HRD + f * HRD;
    ushort* out = B1 + ((size_t)l * DH + f) * DH;
    for (int k = 0; k < DH; ++k) out[k] = f2b(mw[k]);
    for (int r = 0; r < RR; ++r) {
        float acc = 0.f;
        for (int c = 0; c < RDIM; ++c)
            acc += relE[l * RR * RDIM + r * RDIM + c] * mw[DH + c];
        RMt[(size_t)l * DH * RR + f * RR + r] = acc;
    }
}

// Wc2b[l][f][0..127]=self_W, [128..255]=neigh_W  (bf16)
__global__ __launch_bounds__(256) void k_prep_wc2b(const float* __restrict__ selfW,
                                                   const float* __restrict__ neighW,
                                                   ushort* __restrict__ o) {
    int idx = blockIdx.x * 256 + threadIdx.x;        // 65536
    int l = idx >> 15, rem = idx & 32767;
    int f = rem >> 8, k = rem & 255;
    float v = (k < DH) ? selfW[(size_t)l * DH * DH + f * DH + k]
                       : neighW[(size_t)l * DH * DH + f * DH + (k - DH)];
    o[idx] = f2b(v);
}

// ---------------- gather (4-way edge ILP) ----------------
// HS[n][128..255] = sum_{e:dst=n} HS[src_e][0..127];  HS[n][256..383] = sum_e RMt[:][rel_e]
// lane = (q,r): q = edge sub-slot (4 edges in flight), r = 16B column slice.
__global__ __launch_bounds__(256) void k_seg(ushort* __restrict__ hs,
                                             const int* __restrict__ rp,
                                             const int* __restrict__ col,
                                             const float* __restrict__ RMt) {
    __shared__ float RM_s[DH * RR];                   // 8 KB, [col][rel]
    int t = threadIdx.x;
    for (int i = t; i < DH * RR; i += 256) RM_s[i] = RMt[i];
    __syncthreads();
    int wid = t >> 6, lane = t & 63;
    int n = blockIdx.x * 4 + wid;
    if (n >= NN) return;
    int beg = rp[n], end = rp[n + 1];
    int q = lane >> 4, r = lane & 15;
    float a[8], rm[8];
    #pragma unroll
    for (int i = 0; i < 8; ++i) { a[i] = 0.f; rm[i] = 0.f; }
    for (int j0 = beg; j0 < end; j0 += 64) {
        int myc = (j0 + lane < end) ? col[j0 + lane] : 0;
        int mm = min(end - j0, 64);
        #pragma unroll 4
        for (int jj = 0; jj * 4 < mm; ++jj) {
            int idx = jj * 4 + q;
            int packed = __shfl(myc, idx, 64);
            if (idx < mm) {
                int sidx = packed & 0xffff;
                int rel = (packed >> 16) & 15;
                uint4 v = *(const uint4*)(hs + (size_t)sidx * HSW + r * 8);
                const ushort* pv = (const ushort*)&v;
                const float* rmp = RM_s + (r * 8) * RR + rel;
                #pragma unroll
                for (int i = 0; i < 8; ++i) {
                    a[i] += b2f(pv[i]);
                    rm[i] += rmp[i * RR];
                }
            }
        }
    }
    #pragma unroll
    for (int i = 0; i < 8; ++i) {
        a[i] += __shfl_xor(a[i], 16, 64);  a[i] += __shfl_xor(a[i], 32, 64);
        rm[i] += __shfl_xor(rm[i], 16, 64); rm[i] += __shfl_xor(rm[i], 32, 64);
    }
    if (q == 0) {
        uint4 W, R;
        uint* pw = (uint*)&W; uint* pr2 = (uint*)&R;
        #pragma unroll
        for (int i = 0; i < 4; ++i) {
            pw[i]  = (uint)f2b(a[2 * i])  | ((uint)f2b(a[2 * i + 1]) << 16);
            pr2[i] = (uint)f2b(rm[2 * i]) | ((uint)f2b(rm[2 * i + 1]) << 16);
        }
        *(uint4*)(hs + (size_t)n * HSW + 128 + r * 8) = W;
        *(uint4*)(hs + (size_t)n * HSW + 256 + r * 8) = R;
    }
}

// ---------------- MFMA GEMM (unchanged from round 7) ----------------
template <int K, int EPI, int AMODE>
__global__ __launch_bounds__(256) void k_mm(const void* __restrict__ Araw,
                                            const ushort* __restrict__ B,
                                            const float* __restrict__ bias1,
                                            const float* __restrict__ bias2,
                                            const int* __restrict__ deg,
                                            ushort* __restrict__ hs,
                                            float* __restrict__ outf) {
    constexpr int KC = (K == 256) ? 128 : K;
    constexpr int NCH = K / KC;
    constexpr int KP = KC + 8;
    __shared__ ushort A_s[64][KP];
    __shared__ ushort B_s[128][KP];
    __shared__ int deg_s[64];
    int t = threadIdx.x;
    int n0 = blockIdx.x * 64;
    int lane = t & 63, wid = t >> 6;
    int wm = wid >> 1, wn = wid & 1;

    if (EPI == 1 && t < 64) {
        int node = n0 + t;
        deg_s[t] = (node < NN) ? deg[node] : 1;
    }

    f32x4 acc[2][4];
    #pragma unroll
    for (int mt = 0; mt < 2; ++mt)
        #pragma unroll
        for (int nt = 0; nt < 4; ++nt) acc[mt][nt] = (f32x4)0.0f;

    for (int ch = 0; ch < NCH; ++ch) {
        int kc0 = ch * KC;
        if (AMODE == 0) {
            const float4* x4 = (const float4*)Araw;            // [NN][128] f32
            for (int idx = t; idx < 64 * (KC / 4); idx += 256) {
                int r = idx / (KC / 4), c = idx % (KC / 4);
                int node = min(n0 + r, NN - 1);
                float4 v = x4[(size_t)node * 32 + c];
                ushort* dstp = &A_s[r][c * 4];
                dstp[0] = f2b(v.x); dstp[1] = f2b(v.y);
                dstp[2] = f2b(v.z); dstp[3] = f2b(v.w);
            }
        } else {
            const ushort* Ab = (const ushort*)Araw;
            for (int idx = t; idx < 64 * (KC / 8); idx += 256) {
                int r = idx / (KC / 8), c = idx % (KC / 8);
                int node = min(n0 + r, NN - 1);
                *(uint4*)&A_s[r][c * 8] =
                    *(const uint4*)(Ab + (size_t)node * HSW + kc0 + c * 8);
            }
        }
        for (int idx = t; idx < 128 * (KC / 8); idx += 256) {
            int r = idx / (KC / 8), c = idx % (KC / 8);
            *(uint4*)&B_s[r][c * 8] =
                *(const uint4*)(B + (size_t)r * K + kc0 + c * 8);
        }
        __syncthreads();

        #pragma unroll
        for (int ks = 0; ks < KC / 32; ++ks) {
            int k0 = ks * 32 + (lane >> 4) * 8;
            bf16x8 af[2], bfr[4];
            #pragma unroll
            for (int mt = 0; mt < 2; ++mt)
                af[mt] = *(const bf16x8*)&A_s[wm * 32 + mt * 16 + (lane & 15)][k0];
            #pragma unroll
            for (int nt = 0; nt < 4; ++nt)
                bfr[nt] = *(const bf16x8*)&B_s[wn * 64 + nt * 16 + (lane & 15)][k0];
            #pragma unroll
            for (int mt = 0; mt < 2; ++mt)
                #pragma unroll
                for (int nt = 0; nt < 4; ++nt)
                    acc[mt][nt] = __builtin_amdgcn_mfma_f32_16x16x32_bf16(
                        af[mt], bfr[nt], acc[mt][nt], 0, 0, 0);
        }
        if (ch + 1 < NCH) __syncthreads();
    }

    int fbase = wn * 64;
    #pragma unroll
    for (int mt = 0; mt < 2; ++mt) {
        #pragma unroll
        for (int rg = 0; rg < 4; ++rg) {
            int nl = wm * 32 + mt * 16 + ((lane >> 4) << 2) + rg;
            int node = n0 + nl;
            if (node >= NN) continue;
            #pragma unroll
            for (int nt = 0; nt < 4; ++nt) {
                int f = fbase + nt * 16 + (lane & 15);
                float v = acc[mt][nt][rg];
                if (EPI == 0) {
                    hs[(size_t)node * HSW + f] = f2b(v + bias1[f]);
                } else if (EPI == 1) {
                    int d = deg_s[nl];
                    float rmacc = b2f(hs[(size_t)node * HSW + 256 + f]);
                    float o = (v + rmacc) * (1.f / (float)max(d, 1))
                              + ((d > 0) ? bias1[f] : 0.f);
                    hs[(size_t)node * HSW + 128 + f] = f2b(o);
                } else {
                    float o = fmaxf(v + bias1[f] + bias2[f], 0.f);
                    if (EPI == 2) hs[(size_t)node * HSW + f] = f2b(o);
                    else          outf[(size_t)node * DH + f] = o;
                }
            }
        }
    }
}

// ---------------- launch ----------------
extern "C" void kernel_launch(void* const* d_in, const int* in_sizes, int n_in,
                              void* d_out, int out_size, void* d_ws, size_t ws_size,
                              hipStream_t stream) {
    const float* x      = (const float*)d_in[0];
    const float* in_W   = (const float*)d_in[1];
    const float* in_b   = (const float*)d_in[2];
    const float* rel_e  = (const float*)d_in[3];
    const float* msg_W  = (const float*)d_in[4];
    const float* msg_b  = (const float*)d_in[5];
    const float* self_W = (const float*)d_in[6];
    const float* self_b = (const float*)d_in[7];
    const float* neigh_W= (const float*)d_in[8];
    const float* neigh_b= (const float*)d_in[9];
    const int* e_src    = (const int*)d_in[10];
    const int* e_dst    = (const int*)d_in[11];
    const int* r_ids    = (const int*)d_in[12];

    char* ws = (char*)d_ws;
    size_t off = 0;
    ushort* HS   = (ushort*)(ws + off); off += (size_t)NN * HSW * 2;      // 38.4 MB
    ushort* inWb = (ushort*)(ws + off); off += (size_t)DH * DH * 2;
    ushort* B1   = (ushort*)(ws + off); off += 2 * (size_t)DH * DH * 2;
    ushort* Wc2b = (ushort*)(ws + off); off += 2 * (size_t)DH * 256 * 2;
    float*  RMt  = (float*)(ws + off);  off += 2 * (size_t)DH * RR * 4;
    int* deg  = (int*)(ws + off);
    int* rp   = deg + NN;
    int* bsum = rp + NN + 1;
    int* boff = bsum + 256;
    int* ord  = boff + 256;
    int* col  = ord + EE;                                                 // total ~45 MB

    hipMemsetAsync(deg, 0, sizeof(int) * NN, stream);

    k_count<<<(EE + 255) / 256, 256, 0, stream>>>(e_dst, deg, ord);
    k_scan_part<<<SCAN_B, 256, 0, stream>>>(deg, rp, bsum);
    k_scan_bsum<<<1, 256, 0, stream>>>(bsum, boff);
    k_scan_add<<<SCAN_B, 256, 0, stream>>>(boff, rp);
    k_fill<<<(EE + 255) / 256, 256, 0, stream>>>(e_src, e_dst, r_ids, ord, rp, col);

    k_prep_inWb<<<64, 256, 0, stream>>>(in_W, inWb);
    k_prep_msgWb<<<1, 256, 0, stream>>>(msg_W, rel_e, B1, RMt);
    k_prep_wc2b<<<256, 256, 0, stream>>>(self_W, neigh_W, Wc2b);

    const int GB = (NN + 63) / 64;   // 782
    // h = x @ in_W.T + in_b   -> HS[:,0:128] bf16
    k_mm<128, 0, 0><<<GB, 256, 0, stream>>>(x, inWb, in_b, nullptr, nullptr, HS, nullptr);

    for (int l = 0; l < 2; ++l) {
        k_seg<<<(NN + 3) / 4, 256, 0, stream>>>(HS, rp, col, RMt + (size_t)l * DH * RR);
        // agg = (S@msg_Wh.T + RMacc)/max(deg,1) + (deg>0)*msg_b  -> HS[:,128:256]
        k_mm<128, 1, 1><<<GB, 256, 0, stream>>>(HS + 128, B1 + (size_t)l * DH * DH,
                                                msg_b + l * DH, nullptr, deg, HS, nullptr);
        if (l == 0)
            k_mm<256, 2, 1><<<GB, 256, 0, stream>>>(HS, Wc2b, self_b, neigh_b,
                                                    nullptr, HS, nullptr);
        else
            k_mm<256, 3, 1><<<GB, 256, 0, stream>>>(HS, Wc2b + (size_t)DH * 256,
                                                    self_b + DH, neigh_b + DH,
                                                    nullptr, HS, (float*)d_out);
    }
}